// Round 1
// baseline (832.592 us; speedup 1.0000x reference)
//
#include <hip/hip_runtime.h>
#include <math.h>

#define BB 2
#define NN 16000
#define EE 160000
#define KK 128
#define CC 64
#define LL 3
#define RDIM 448        // 128 cos + 128 sin + 64 h + 128 seg
#define S1 125          // x-splits for forward transform
#define XR 128          // N / S1

__device__ __forceinline__ float gelu_f(float x){
    float x3 = x * x * x;
    return 0.5f * x * (1.f + tanhf(0.7978845608028654f * (x + 0.044715f * x3)));
}

// ---------------------------------------------------------------- bases
__global__ __launch_bounds__(256) void k_bases(
    const float* __restrict__ nodes, const float* __restrict__ modes,
    const float* __restrict__ latent, float* __restrict__ cb, float* __restrict__ sb){
    int bid = blockIdx.x;              // B * 500
    int b = bid / 500, x0 = (bid % 500) * 32;
    int t = threadIdx.x;
    __shared__ float sm0[128], sm1[128];
    if (t < 128){
        float i0 = 0.5f + 1.5f / (1.f + expf(-latent[0]));
        float i1 = 0.5f + 1.5f / (1.f + expf(-latent[1]));
        sm0[t] = modes[t*2+0] * i0;
        sm1[t] = modes[t*2+1] * i1;
    }
    __syncthreads();
    int k = t & 127, xh = t >> 7;
    for (int p = 0; p < 16; p++){
        int x = x0 + p*2 + xh;
        size_t nb = (size_t)b*NN + x;
        float n0 = nodes[nb*2], n1 = nodes[nb*2+1];
        float tmp = n0*sm0[k] + n1*sm1[k];
        float sv, cv; sincosf(tmp, &sv, &cv);
        cb[nb*KK + k] = cv;
        sb[nb*KK + k] = sv;
    }
}

// ---------------------------------------------------------------- fc0
__global__ __launch_bounds__(256) void k_fc0(
    const float* __restrict__ x, const float* __restrict__ W,
    const float* __restrict__ bb, float* __restrict__ h0){
    int bid = blockIdx.x;              // B * 250
    int b = bid / 250, x0 = (bid % 250) * 64;
    int t = threadIdx.x, o = t & 63, xg = t >> 6;
    float w0 = W[o*3], w1 = W[o*3+1], w2 = W[o*3+2], bo = bb[o];
    for (int xi = xg; xi < 64; xi += 4){
        size_t xb = (size_t)b*NN + x0 + xi;
        float v0 = x[xb*3], v1 = x[xb*3+1], v2 = x[xb*3+2];
        h0[xb*CC + o] = w0*v0 + w1*v1 + w2*v2 + bo;
    }
}

// ---------------------------------------------------------------- CSR build
__global__ __launch_bounds__(256) void csr_hist(
    const int* __restrict__ edges, int* __restrict__ cnt){
    int idx = blockIdx.x * 256 + threadIdx.x;
    if (idx >= BB*EE) return;
    int b = idx / EE;
    int tgt = edges[(size_t)idx*2];
    atomicAdd(&cnt[b*NN + tgt], 1);
}

__global__ __launch_bounds__(1024) void csr_scan(
    const int* __restrict__ cnt, int* __restrict__ rowptr, int* __restrict__ cursor){
    int b = blockIdx.x;
    int t = threadIdx.x;
    __shared__ int lds[1024];
    int base = t * 16;
    int v[16];
    int run = 0;
    #pragma unroll
    for (int j = 0; j < 16; j++){
        int n = base + j;
        int c = (n < NN) ? cnt[b*NN + n] : 0;
        v[j] = run;
        run += c;
    }
    lds[t] = run;
    __syncthreads();
    for (int off = 1; off < 1024; off <<= 1){
        int xv = (t >= off) ? lds[t-off] : 0;
        __syncthreads();
        lds[t] += xv;
        __syncthreads();
    }
    int toff = lds[t] - run;  // exclusive
    #pragma unroll
    for (int j = 0; j < 16; j++){
        int n = base + j;
        if (n < NN){
            int p = toff + v[j];
            rowptr[b*(NN+1) + n] = p;
            cursor[b*NN + n] = p;
        }
    }
    if (t == 1023) rowptr[b*(NN+1) + NN] = lds[1023];
}

__global__ __launch_bounds__(256) void csr_fill(
    const int* __restrict__ edges, const float* __restrict__ egw,
    int* __restrict__ cursor, int* __restrict__ insrc, float2* __restrict__ inw){
    int idx = blockIdx.x * 256 + threadIdx.x;
    if (idx >= BB*EE) return;
    int b = idx / EE;
    int tgt = edges[(size_t)idx*2];
    int src = edges[(size_t)idx*2 + 1];
    int pos = atomicAdd(&cursor[b*NN + tgt], 1);
    insrc[(size_t)b*EE + pos] = src;
    const float2 wv = *(const float2*)&egw[(size_t)idx*2];
    inw[(size_t)b*EE + pos] = wv;
}

// ---------------------------------------------------------------- forward transform (partials)
__global__ __launch_bounds__(256) void k1_fwd(
    const float* __restrict__ h, const float* __restrict__ cb,
    const float* __restrict__ sb, const float* __restrict__ nw,
    float* __restrict__ partC, float* __restrict__ partS, float* __restrict__ part0){
    int bid = blockIdx.x;              // B * S1
    int b = bid / S1, s = bid % S1;
    int t = threadIdx.x;
    __shared__ __align__(16) float hT[16][64];
    __shared__ __align__(16) float wcT[16][128];
    __shared__ __align__(16) float wsT[16][128];
    __shared__ float wv[16];
    int kg = t & 15, ig = t >> 4;
    float accC[4][8] = {};
    float accS[4][8] = {};
    float acc0[4] = {};
    int xbase = s * XR;
    for (int ch = 0; ch < XR/16; ch++){
        int xs = xbase + ch*16;
        {   // stage h tile (16 x 64)
            int xx = t >> 4, cq = t & 15;
            float4 hv = *(const float4*)&h[((size_t)b*NN + xs + xx)*CC + cq*4];
            *(float4*)&hT[xx][cq*4] = hv;
        }
        if (t < 16) wv[t] = nw[b*NN + xs + t];
        #pragma unroll
        for (int rep = 0; rep < 2; rep++){
            int u = rep*256 + t;       // 0..511
            int xx = u >> 5, kq = u & 31;
            float wgt = nw[b*NN + xs + xx];
            size_t gb = ((size_t)b*NN + xs + xx)*KK + kq*4;
            float4 cv = *(const float4*)&cb[gb];
            float4 sv = *(const float4*)&sb[gb];
            cv.x *= wgt; cv.y *= wgt; cv.z *= wgt; cv.w *= wgt;
            sv.x *= wgt; sv.y *= wgt; sv.z *= wgt; sv.w *= wgt;
            *(float4*)&wcT[xx][kq*4] = cv;
            *(float4*)&wsT[xx][kq*4] = sv;
        }
        __syncthreads();
        #pragma unroll
        for (int xx = 0; xx < 16; xx++){
            float4 hv = *(float4*)&hT[xx][ig*4];
            float ha[4] = {hv.x, hv.y, hv.z, hv.w};
            float wgt = wv[xx];
            #pragma unroll
            for (int ii = 0; ii < 4; ii++) acc0[ii] += ha[ii] * wgt;
            #pragma unroll
            for (int j = 0; j < 8; j++){
                int k = kg + 16*j;
                float cv = wcT[xx][k];
                float sv = wsT[xx][k];
                #pragma unroll
                for (int ii = 0; ii < 4; ii++){
                    accC[ii][j] += ha[ii] * cv;
                    accS[ii][j] += ha[ii] * sv;
                }
            }
        }
        __syncthreads();
    }
    size_t pbase = (size_t)(b*S1 + s) * CC;
    #pragma unroll
    for (int ii = 0; ii < 4; ii++){
        int i = ig*4 + ii;
        #pragma unroll
        for (int j = 0; j < 8; j++){
            int k = kg + 16*j;
            partC[(pbase + i)*KK + k] = accC[ii][j];
            partS[(pbase + i)*KK + k] = accS[ii][j];
        }
        if (kg == 0) part0[pbase + i] = acc0[ii];
    }
}

__global__ __launch_bounds__(256) void k1_reduce(
    const float* __restrict__ partC, const float* __restrict__ partS,
    float* __restrict__ Sc, float* __restrict__ Ss){
    int b = blockIdx.x >> 3;           // grid B*8
    int blk = blockIdx.x & 7;
    int q0 = blk*1024 + threadIdx.x;
    for (int r = 0; r < 4; r++){
        int q = q0 + r*256;
        float sc = 0.f, ss = 0.f;
        for (int s = 0; s < S1; s++){
            sc += partC[(size_t)(b*S1+s)*8192 + q];
            ss += partS[(size_t)(b*S1+s)*8192 + q];
        }
        Sc[b*8192 + q] = sc;
        Ss[b*8192 + q] = ss;
    }
}

// ---------------------------------------------------------------- per-mode channel mix -> Wbig, bias
__global__ __launch_bounds__(256) void k2_mix(
    const float* __restrict__ Sc, const float* __restrict__ Ss,
    const float* __restrict__ part0,
    const float* __restrict__ wc, const float* __restrict__ wsp,
    const float* __restrict__ w0,
    const float* __restrict__ wsb, const float* __restrict__ gwsb,
    const float* __restrict__ wsW, const float* __restrict__ gwsW,
    float* __restrict__ Wbig, float* __restrict__ bias, int l){
    int b = blockIdx.x >> 6, o = blockIdx.x & 63;
    int t = threadIdx.x;
    __shared__ float fc2s[2][128], fs2s[2][128];
    __shared__ float red[64];
    if (t < 64){
        float x0 = 0.f;
        for (int s = 0; s < S1; s++) x0 += part0[(b*S1+s)*CC + t];
        red[t] = x0 * w0[((size_t)l*CC + t)*CC + o];
    }
    int k = t & 127, hf = t >> 7;
    float fc = 0.f, fs = 0.f;
    for (int i = hf*32; i < hf*32 + 32; i++){
        float sc = Sc[(b*CC + i)*KK + k];
        float ss = Ss[(b*CC + i)*KK + k];
        size_t wi = (((size_t)l*CC + i)*CC + o)*KK + k;
        float a = wc[wi], bb2 = wsp[wi];
        fc += sc*a + ss*bb2;
        fs += sc*bb2 - ss*a;
    }
    fc2s[hf][k] = fc; fs2s[hf][k] = fs;
    __syncthreads();
    size_t wb = ((size_t)b*CC + o) * RDIM;
    if (t < 128){
        float FC = fc2s[0][t] + fc2s[1][t];
        float FS = fs2s[0][t] + fs2s[1][t];
        Wbig[wb + t] = 2.f * FC;
        Wbig[wb + 128 + t] = -2.f * FS;
    }
    if (t < 64) Wbig[wb + 256 + t] = wsW[((size_t)l*CC + o)*CC + t];
    if (t >= 64 && t < 192) Wbig[wb + 320 + (t-64)] = gwsW[((size_t)l*CC + o)*128 + (t-64)];
    if (t == 0){
        float f0 = 0.f;
        for (int i = 0; i < 64; i++) f0 += red[i];
        bias[b*CC + o] = f0 + wsb[l*CC + o] + gwsb[l*CC + o];
    }
}

// ---------------------------------------------------------------- gradient field (CSR, atomic-free)
__global__ __launch_bounds__(256) void k_grad(
    const float* __restrict__ h, const int* __restrict__ rowptr,
    const int* __restrict__ insrc, const float2* __restrict__ inw,
    float* __restrict__ seg){
    int bid = blockIdx.x;              // B * 250
    int b = bid / 250, n0 = (bid % 250) * 64;
    int w = threadIdx.x >> 6, c = threadIdx.x & 63;
    for (int g = 0; g < 16; g++){
        int n = n0 + w*16 + g;
        float hn = h[((size_t)b*NN + n)*CC + c];
        int p0 = rowptr[b*(NN+1) + n];
        int p1 = rowptr[b*(NN+1) + n + 1];
        float a0 = 0.f, a1 = 0.f;
        for (int p = p0; p < p1; p++){
            int sidx = insrc[(size_t)b*EE + p];
            float2 w2 = inw[(size_t)b*EE + p];
            float d = h[((size_t)b*NN + sidx)*CC + c] - hn;
            a0 += w2.x * d;
            a1 += w2.y * d;
        }
        *(float2*)&seg[((size_t)b*NN + n)*128 + 2*c] = make_float2(a0, a1);
    }
}

// ---------------------------------------------------------------- layer output GEMM: h_new = gelu(Wbig @ V + bias)
__global__ __launch_bounds__(256) void k3_gemm(
    const float* __restrict__ Wbig, const float* __restrict__ bias,
    const float* __restrict__ cbase, const float* __restrict__ sbase,
    const float* __restrict__ h, const float* __restrict__ seg,
    float* __restrict__ hout, int applyGelu){
    int bid = blockIdx.x;              // B * 250
    int b = bid / 250, x0 = (bid % 250) * 64;
    int t = threadIdx.x;
    __shared__ __align__(16) float Wl[32][68];
    __shared__ __align__(16) float Vl[32][68];
    int to = t & 15, tx = t >> 4;
    int o0 = to*4, xl = tx*4;
    float acc[4][4] = {};               // [x][o]
    for (int ch = 0; ch < 14; ch++){
        const float* src; int kb, rl;
        if (ch < 4){ src = cbase; kb = ch*32; rl = 128; }
        else if (ch < 8){ src = sbase; kb = (ch-4)*32; rl = 128; }
        else if (ch < 10){ src = h; kb = (ch-8)*32; rl = 64; }
        else { src = seg; kb = (ch-10)*32; rl = 128; }
        #pragma unroll
        for (int rep = 0; rep < 2; rep++){
            int u = rep*256 + t;       // 0..511
            int xx = u >> 3, kq = u & 7;
            float4 v = *(const float4*)&src[((size_t)b*NN + x0 + xx)*rl + kb + kq*4];
            Vl[kq*4+0][xx] = v.x; Vl[kq*4+1][xx] = v.y;
            Vl[kq*4+2][xx] = v.z; Vl[kq*4+3][xx] = v.w;
        }
        #pragma unroll
        for (int rep = 0; rep < 2; rep++){
            int u = rep*256 + t;
            int oo = u >> 3, kq = u & 7;
            float4 v = *(const float4*)&Wbig[((size_t)b*CC + oo)*RDIM + ch*32 + kq*4];
            Wl[kq*4+0][oo] = v.x; Wl[kq*4+1][oo] = v.y;
            Wl[kq*4+2][oo] = v.z; Wl[kq*4+3][oo] = v.w;
        }
        __syncthreads();
        #pragma unroll
        for (int kk = 0; kk < 32; kk++){
            float4 wvec = *(float4*)&Wl[kk][o0];
            float4 vvec = *(float4*)&Vl[kk][xl];
            float wa[4] = {wvec.x, wvec.y, wvec.z, wvec.w};
            float va[4] = {vvec.x, vvec.y, vvec.z, vvec.w};
            #pragma unroll
            for (int j = 0; j < 4; j++)
                #pragma unroll
                for (int i = 0; i < 4; i++)
                    acc[j][i] += va[j] * wa[i];
        }
        __syncthreads();
    }
    float bs[4];
    #pragma unroll
    for (int i = 0; i < 4; i++) bs[i] = bias[b*CC + o0 + i];
    #pragma unroll
    for (int j = 0; j < 4; j++){
        float4 r;
        r.x = acc[j][0] + bs[0];
        r.y = acc[j][1] + bs[1];
        r.z = acc[j][2] + bs[2];
        r.w = acc[j][3] + bs[3];
        if (applyGelu){
            r.x = gelu_f(r.x); r.y = gelu_f(r.y);
            r.z = gelu_f(r.z); r.w = gelu_f(r.w);
        }
        *(float4*)&hout[((size_t)b*NN + x0 + xl + j)*CC + o0] = r;
    }
}

// ---------------------------------------------------------------- head: gelu(fc1) -> fc2
__global__ __launch_bounds__(256) void k_head(
    const float* __restrict__ h, const float* __restrict__ W1,
    const float* __restrict__ b1, const float* __restrict__ W2,
    const float* __restrict__ b2, float* __restrict__ out){
    int bid = blockIdx.x;              // B * 250
    int b = bid / 250, n0 = (bid % 250) * 64;
    int t = threadIdx.x, w = t >> 6, f = t & 63;
    __shared__ float Wl[128][65];
    __shared__ float hl[4][64];
    #pragma unroll
    for (int r = 0; r < 8; r++){
        int u = r*256 + t;
        int ff = u >> 4, cq = u & 15;
        float4 v = *(const float4*)&W1[ff*64 + cq*4];
        Wl[ff][cq*4+0] = v.x; Wl[ff][cq*4+1] = v.y;
        Wl[ff][cq*4+2] = v.z; Wl[ff][cq*4+3] = v.w;
    }
    __syncthreads();
    float w2a = W2[f], w2b = W2[64+f];
    float b1a = b1[f], b1b = b1[64+f];
    for (int g = 0; g < 16; g++){
        int n = n0 + w*16 + g;
        hl[w][f] = h[((size_t)b*NN + n)*CC + f];
        __syncthreads();
        float a1 = b1a, a2 = b1b;
        #pragma unroll
        for (int c2 = 0; c2 < 64; c2++){
            float hv = hl[w][c2];
            a1 += Wl[f][c2] * hv;
            a2 += Wl[64+f][c2] * hv;
        }
        float p = gelu_f(a1)*w2a + gelu_f(a2)*w2b;
        for (int off = 32; off; off >>= 1) p += __shfl_down(p, off, 64);
        if (f == 0) out[(size_t)b*NN + n] = p + b2[0];
        __syncthreads();
    }
}

// ---------------------------------------------------------------- host
extern "C" void kernel_launch(void* const* d_in, const int* in_sizes, int n_in,
                              void* d_out, int out_size, void* d_ws, size_t ws_size,
                              hipStream_t stream){
    const float* x_in  = (const float*)d_in[0];
    const float* nodes = (const float*)d_in[2];
    const float* nw    = (const float*)d_in[3];
    const int*   edges = (const int*)d_in[4];
    const float* egw   = (const float*)d_in[5];
    const float* modes = (const float*)d_in[6];
    const float* latent= (const float*)d_in[7];
    const float* fc0W  = (const float*)d_in[8];
    const float* fc0b  = (const float*)d_in[9];
    const float* wc    = (const float*)d_in[10];
    const float* wsp   = (const float*)d_in[11];
    const float* w0    = (const float*)d_in[12];
    const float* wsW   = (const float*)d_in[13];
    const float* wsb   = (const float*)d_in[14];
    const float* gwsW  = (const float*)d_in[15];
    const float* gwsb  = (const float*)d_in[16];
    const float* fc1W  = (const float*)d_in[17];
    const float* fc1b  = (const float*)d_in[18];
    const float* fc2W  = (const float*)d_in[19];
    const float* fc2b  = (const float*)d_in[20];
    float* out = (float*)d_out;

    char* wsbase = (char*)d_ws;
    size_t off = 0;
    auto alloc = [&](size_t bytes) -> void* {
        void* p = wsbase + off;
        off += (bytes + 255) & ~(size_t)255;
        return p;
    };
    float* cb    = (float*)alloc((size_t)BB*NN*KK*4);
    float* sb    = (float*)alloc((size_t)BB*NN*KK*4);
    float* h0    = (float*)alloc((size_t)BB*NN*CC*4);
    float* h1    = (float*)alloc((size_t)BB*NN*CC*4);
    float* seg   = (float*)alloc((size_t)BB*NN*2*CC*4);
    float* partC = (float*)alloc((size_t)BB*S1*CC*KK*4);
    float* partS = (float*)alloc((size_t)BB*S1*CC*KK*4);
    float* part0 = (float*)alloc((size_t)BB*S1*CC*4);
    float* Sc    = (float*)alloc((size_t)BB*CC*KK*4);
    float* Ss    = (float*)alloc((size_t)BB*CC*KK*4);
    float* Wbig  = (float*)alloc((size_t)BB*CC*RDIM*4);
    float* bias  = (float*)alloc((size_t)BB*CC*4);
    int*   cnt   = (int*)alloc((size_t)BB*NN*4);
    int*   rowptr= (int*)alloc((size_t)BB*(NN+4)*4);
    int*   cursor= (int*)alloc((size_t)BB*NN*4);
    int*   insrc = (int*)alloc((size_t)BB*EE*4);
    float2* inw  = (float2*)alloc((size_t)BB*EE*8);

    // bases + fc0
    k_bases<<<BB*500, 256, 0, stream>>>(nodes, modes, latent, cb, sb);
    k_fc0<<<BB*250, 256, 0, stream>>>(x_in, fc0W, fc0b, h0);

    // CSR build
    hipMemsetAsync(cnt, 0, (size_t)BB*NN*4, stream);
    csr_hist<<<(BB*EE+255)/256, 256, 0, stream>>>(edges, cnt);
    csr_scan<<<BB, 1024, 0, stream>>>(cnt, rowptr, cursor);
    csr_fill<<<(BB*EE+255)/256, 256, 0, stream>>>(edges, egw, cursor, insrc, inw);

    float* hcur = h0;
    float* hnext = h1;
    for (int l = 0; l < LL; l++){
        k1_fwd<<<BB*S1, 256, 0, stream>>>(hcur, cb, sb, nw, partC, partS, part0);
        k1_reduce<<<BB*8, 256, 0, stream>>>(partC, partS, Sc, Ss);
        k2_mix<<<BB*CC, 256, 0, stream>>>(Sc, Ss, part0, wc, wsp, w0, wsb, gwsb,
                                          wsW, gwsW, Wbig, bias, l);
        k_grad<<<BB*250, 256, 0, stream>>>(hcur, rowptr, insrc, inw, seg);
        k3_gemm<<<BB*250, 256, 0, stream>>>(Wbig, bias, cb, sb, hcur, seg, hnext,
                                            (l < LL-1) ? 1 : 0);
        float* tmp = hcur; hcur = hnext; hnext = tmp;
    }
    // head (hcur holds final h)
    k_head<<<BB*250, 256, 0, stream>>>(hcur, fc1W, fc1b, fc2W, fc2b, out);
    (void)in_sizes; (void)n_in; (void)out_size; (void)ws_size;
}

// Round 2
// 521.380 us; speedup vs baseline: 1.5969x; 1.5969x over previous
//
#include <hip/hip_runtime.h>
#include <math.h>

#define BB 2
#define NN 16000
#define EE 160000
#define KK 128
#define CC 64
#define LL 3
#define RDIM 448        // 128 cos + 128 sin + 64 h + 128 seg
#define S1 125          // x-splits for forward transform
#define XR 128          // N / S1

__device__ __forceinline__ float gelu_f(float x){
    float x3 = x * x * x;
    return 0.5f * x * (1.f + tanhf(0.7978845608028654f * (x + 0.044715f * x3)));
}

__device__ __forceinline__ void gl2lds16(const float* g, float* l){
    __builtin_amdgcn_global_load_lds(
        (const __attribute__((address_space(1))) void*)g,
        (__attribute__((address_space(3))) void*)l, 16, 0, 0);
}

// ---------------------------------------------------------------- bases
__global__ __launch_bounds__(256) void k_bases(
    const float* __restrict__ nodes, const float* __restrict__ modes,
    const float* __restrict__ latent, float* __restrict__ cb, float* __restrict__ sb){
    int bid = blockIdx.x;              // B * 500
    int b = bid / 500, x0 = (bid % 500) * 32;
    int t = threadIdx.x;
    __shared__ float sm0[128], sm1[128];
    if (t < 128){
        float i0 = 0.5f + 1.5f / (1.f + expf(-latent[0]));
        float i1 = 0.5f + 1.5f / (1.f + expf(-latent[1]));
        sm0[t] = modes[t*2+0] * i0;
        sm1[t] = modes[t*2+1] * i1;
    }
    __syncthreads();
    int k = t & 127, xh = t >> 7;
    for (int p = 0; p < 16; p++){
        int x = x0 + p*2 + xh;
        size_t nb = (size_t)b*NN + x;
        float n0 = nodes[nb*2], n1 = nodes[nb*2+1];
        float tmp = n0*sm0[k] + n1*sm1[k];
        float sv, cv; sincosf(tmp, &sv, &cv);
        cb[nb*KK + k] = cv;
        sb[nb*KK + k] = sv;
    }
}

// ---------------------------------------------------------------- fc0
__global__ __launch_bounds__(256) void k_fc0(
    const float* __restrict__ x, const float* __restrict__ W,
    const float* __restrict__ bb, float* __restrict__ h0){
    int bid = blockIdx.x;              // B * 250
    int b = bid / 250, x0 = (bid % 250) * 64;
    int t = threadIdx.x, o = t & 63, xg = t >> 6;
    float w0 = W[o*3], w1 = W[o*3+1], w2 = W[o*3+2], bo = bb[o];
    for (int xi = xg; xi < 64; xi += 4){
        size_t xb = (size_t)b*NN + x0 + xi;
        float v0 = x[xb*3], v1 = x[xb*3+1], v2 = x[xb*3+2];
        h0[xb*CC + o] = w0*v0 + w1*v1 + w2*v2 + bo;
    }
}

// ---------------------------------------------------------------- CSR build
__global__ __launch_bounds__(256) void csr_hist(
    const int* __restrict__ edges, int* __restrict__ cnt){
    int idx = blockIdx.x * 256 + threadIdx.x;
    if (idx >= BB*EE) return;
    int b = idx / EE;
    int tgt = edges[(size_t)idx*2];
    atomicAdd(&cnt[b*NN + tgt], 1);
}

__global__ __launch_bounds__(1024) void csr_scan(
    const int* __restrict__ cnt, int* __restrict__ rowptr, int* __restrict__ cursor){
    int b = blockIdx.x;
    int t = threadIdx.x;
    __shared__ int lds[1024];
    int base = t * 16;
    int v[16];
    int run = 0;
    #pragma unroll
    for (int j = 0; j < 16; j++){
        int n = base + j;
        int c = (n < NN) ? cnt[b*NN + n] : 0;
        v[j] = run;
        run += c;
    }
    lds[t] = run;
    __syncthreads();
    for (int off = 1; off < 1024; off <<= 1){
        int xv = (t >= off) ? lds[t-off] : 0;
        __syncthreads();
        lds[t] += xv;
        __syncthreads();
    }
    int toff = lds[t] - run;  // exclusive
    #pragma unroll
    for (int j = 0; j < 16; j++){
        int n = base + j;
        if (n < NN){
            int p = toff + v[j];
            rowptr[b*(NN+1) + n] = p;
            cursor[b*NN + n] = p;
        }
    }
    if (t == 1023) rowptr[b*(NN+1) + NN] = lds[1023];
}

__global__ __launch_bounds__(256) void csr_fill(
    const int* __restrict__ edges, const float* __restrict__ egw,
    int* __restrict__ cursor, int* __restrict__ insrc, float2* __restrict__ inw){
    int idx = blockIdx.x * 256 + threadIdx.x;
    if (idx >= BB*EE) return;
    int b = idx / EE;
    int tgt = edges[(size_t)idx*2];
    int src = edges[(size_t)idx*2 + 1];
    int pos = atomicAdd(&cursor[b*NN + tgt], 1);
    insrc[(size_t)b*EE + pos] = src;
    const float2 wv = *(const float2*)&egw[(size_t)idx*2];
    inw[(size_t)b*EE + pos] = wv;
}

// ---------------------------------------------------------------- forward transform (partials)
struct FwdBuf {
    float hT[16*64];
    float wcT[16*128];
    float wsT[16*128];
    float wv[16];
};

__global__ __launch_bounds__(256) void k1_fwd(
    const float* __restrict__ h, const float* __restrict__ cb,
    const float* __restrict__ sb, const float* __restrict__ nw,
    float* __restrict__ partC, float* __restrict__ partS, float* __restrict__ part0){
    int bid = blockIdx.x;              // B * S1
    int b = bid / S1, s = bid % S1;
    int t = threadIdx.x;
    __shared__ __align__(16) FwdBuf bufs[2];
    int kg = t & 15, ig = t >> 4;
    float accC[4][8] = {};
    float accS[4][8] = {};
    float acc0[4] = {};
    int xbase = s * XR;

    auto STAGE = [&](FwdBuf* d, int ch){
        int xs = xbase + ch*16;
        const float* hb  = &h [((size_t)b*NN + xs)*CC];
        const float* cbb = &cb[((size_t)b*NN + xs)*KK];
        const float* sbb = &sb[((size_t)b*NN + xs)*KK];
        gl2lds16(hb + t*4, &d->hT[(t>>6)*256]);
        #pragma unroll
        for (int rep = 0; rep < 2; rep++){
            int u = rep*256 + t;
            gl2lds16(cbb + u*4, &d->wcT[(u>>6)*256]);
            gl2lds16(sbb + u*4, &d->wsT[(u>>6)*256]);
        }
        if (t < 16) d->wv[t] = nw[b*NN + xs + t];
    };

    STAGE(&bufs[0], 0);
    int cur = 0;
    for (int ch = 0; ch < XR/16; ch++){
        __syncthreads();
        if (ch < XR/16 - 1) STAGE(&bufs[cur^1], ch+1);
        FwdBuf* d = &bufs[cur];
        #pragma unroll
        for (int xx = 0; xx < 16; xx++){
            float wgt = d->wv[xx];
            float4 hv = *(float4*)&d->hT[xx*64 + ig*4];
            float ha0 = hv.x*wgt, ha1 = hv.y*wgt, ha2 = hv.z*wgt, ha3 = hv.w*wgt;
            acc0[0] += ha0; acc0[1] += ha1; acc0[2] += ha2; acc0[3] += ha3;
            #pragma unroll
            for (int j = 0; j < 8; j++){
                int kq = kg + 16*j;
                float cv = d->wcT[xx*128 + kq];
                float sv = d->wsT[xx*128 + kq];
                accC[0][j] += ha0*cv; accC[1][j] += ha1*cv;
                accC[2][j] += ha2*cv; accC[3][j] += ha3*cv;
                accS[0][j] += ha0*sv; accS[1][j] += ha1*sv;
                accS[2][j] += ha2*sv; accS[3][j] += ha3*sv;
            }
        }
        cur ^= 1;
    }
    size_t pbase = (size_t)(b*S1 + s) * CC;
    #pragma unroll
    for (int ii = 0; ii < 4; ii++){
        int i = ig*4 + ii;
        #pragma unroll
        for (int j = 0; j < 8; j++){
            int k = kg + 16*j;
            partC[(pbase + i)*KK + k] = accC[ii][j];
            partS[(pbase + i)*KK + k] = accS[ii][j];
        }
        if (kg == 0) part0[pbase + i] = acc0[ii];
    }
}

// ---------------------------------------------------------------- partial reduce (parallel, streaming)
__global__ __launch_bounds__(256) void k1_reduce(
    const float* __restrict__ partC, const float* __restrict__ partS,
    float* __restrict__ Sc, float* __restrict__ Ss){
    int b = blockIdx.x >> 6, i = blockIdx.x & 63;   // grid B*CC
    int t = threadIdx.x;
    int k = t & 127, sh = t >> 7;
    float c0=0,c1=0,c2=0,c3=0, q0=0,q1=0,q2=0,q3=0;
    int s = sh;
    for (; s + 6 < S1; s += 8){
        size_t i0 = ((size_t)(b*S1 + s    )*CC + i)*KK + k;
        size_t i1 = ((size_t)(b*S1 + s + 2)*CC + i)*KK + k;
        size_t i2 = ((size_t)(b*S1 + s + 4)*CC + i)*KK + k;
        size_t i3 = ((size_t)(b*S1 + s + 6)*CC + i)*KK + k;
        c0 += partC[i0]; c1 += partC[i1]; c2 += partC[i2]; c3 += partC[i3];
        q0 += partS[i0]; q1 += partS[i1]; q2 += partS[i2]; q3 += partS[i3];
    }
    for (; s < S1; s += 2){
        size_t i0 = ((size_t)(b*S1 + s)*CC + i)*KK + k;
        c0 += partC[i0]; q0 += partS[i0];
    }
    float sc = (c0+c1)+(c2+c3), ss = (q0+q1)+(q2+q3);
    __shared__ float rC[128], rS[128];
    if (sh){ rC[k] = sc; rS[k] = ss; }
    __syncthreads();
    if (!sh){
        Sc[((size_t)b*CC + i)*KK + k] = sc + rC[k];
        Ss[((size_t)b*CC + i)*KK + k] = ss + rS[k];
    }
}

// ---------------------------------------------------------------- per-mode channel mix -> Wbig, bias
__global__ __launch_bounds__(256) void k2_mix(
    const float* __restrict__ Sc, const float* __restrict__ Ss,
    const float* __restrict__ part0,
    const float* __restrict__ wc, const float* __restrict__ wsp,
    const float* __restrict__ w0,
    const float* __restrict__ wsb, const float* __restrict__ gwsb,
    const float* __restrict__ wsW, const float* __restrict__ gwsW,
    float* __restrict__ Wbig, float* __restrict__ bias, int l){
    int b = blockIdx.x >> 6, o = blockIdx.x & 63;
    int t = threadIdx.x;
    __shared__ float fc2s[2][128], fs2s[2][128];
    __shared__ float red[64];
    if (t < 64){
        float x0 = 0.f;
        for (int s = 0; s < S1; s++) x0 += part0[(b*S1+s)*CC + t];
        red[t] = x0 * w0[((size_t)l*CC + t)*CC + o];
    }
    int k = t & 127, hf = t >> 7;
    float fc = 0.f, fs = 0.f;
    for (int i = hf*32; i < hf*32 + 32; i++){
        float sc = Sc[(b*CC + i)*KK + k];
        float ss = Ss[(b*CC + i)*KK + k];
        size_t wi = (((size_t)l*CC + i)*CC + o)*KK + k;
        float a = wc[wi], bb2 = wsp[wi];
        fc += sc*a + ss*bb2;
        fs += sc*bb2 - ss*a;
    }
    fc2s[hf][k] = fc; fs2s[hf][k] = fs;
    __syncthreads();
    size_t wb = ((size_t)b*CC + o) * RDIM;
    if (t < 128){
        float FC = fc2s[0][t] + fc2s[1][t];
        float FS = fs2s[0][t] + fs2s[1][t];
        Wbig[wb + t] = 2.f * FC;
        Wbig[wb + 128 + t] = -2.f * FS;
    }
    if (t < 64) Wbig[wb + 256 + t] = wsW[((size_t)l*CC + o)*CC + t];
    if (t >= 64 && t < 192) Wbig[wb + 320 + (t-64)] = gwsW[((size_t)l*CC + o)*128 + (t-64)];
    if (t == 0){
        float f0 = 0.f;
        for (int i = 0; i < 64; i++) f0 += red[i];
        bias[b*CC + o] = f0 + wsb[l*CC + o] + gwsb[l*CC + o];
    }
}

// ---------------------------------------------------------------- gradient field (CSR, atomic-free, ILP unroll-4)
__global__ __launch_bounds__(256) void k_grad(
    const float* __restrict__ h, const int* __restrict__ rowptr,
    const int* __restrict__ insrc, const float2* __restrict__ inw,
    float* __restrict__ seg){
    int bid = blockIdx.x;              // B * 1000
    int b = bid / 1000, n0 = (bid % 1000) * 16;
    int w = threadIdx.x >> 6, c = threadIdx.x & 63;
    const float*  hb  = h + (size_t)b*NN*CC;
    const int*    isb = insrc + (size_t)b*EE;
    const float2* iwb = inw + (size_t)b*EE;
    #pragma unroll
    for (int g = 0; g < 4; g++){
        int n = n0 + w*4 + g;
        float hn = hb[(size_t)n*CC + c];
        int p0 = rowptr[b*(NN+1) + n];
        int p1 = rowptr[b*(NN+1) + n + 1];
        float a0 = 0.f, a1 = 0.f;
        int p = p0;
        for (; p + 4 <= p1; p += 4){
            int s0 = isb[p], s1 = isb[p+1], s2 = isb[p+2], s3 = isb[p+3];
            float2 w0 = iwb[p], w1 = iwb[p+1], w2 = iwb[p+2], w3 = iwb[p+3];
            float d0 = hb[(size_t)s0*CC + c] - hn;
            float d1 = hb[(size_t)s1*CC + c] - hn;
            float d2 = hb[(size_t)s2*CC + c] - hn;
            float d3 = hb[(size_t)s3*CC + c] - hn;
            a0 += w0.x*d0 + w1.x*d1 + w2.x*d2 + w3.x*d3;
            a1 += w0.y*d0 + w1.y*d1 + w2.y*d2 + w3.y*d3;
        }
        for (; p < p1; p++){
            int sx = isb[p]; float2 ww = iwb[p];
            float d = hb[(size_t)sx*CC + c] - hn;
            a0 += ww.x*d; a1 += ww.y*d;
        }
        *(float2*)&seg[((size_t)b*NN + n)*128 + 2*c] = make_float2(a0, a1);
    }
}

// ---------------------------------------------------------------- layer output GEMM: h_new = gelu(Wbig @ V + bias)
__global__ __launch_bounds__(256) void k3_gemm(
    const float* __restrict__ Wbig, const float* __restrict__ bias,
    const float* __restrict__ cbase, const float* __restrict__ sbase,
    const float* __restrict__ h, const float* __restrict__ seg,
    float* __restrict__ hout, int applyGelu){
    int bid = blockIdx.x;              // B * 250
    int b = bid / 250, x0 = (bid % 250) * 64;
    int t = threadIdx.x;
    __shared__ __align__(16) float Wl[32][68];
    __shared__ __align__(16) float Vl[32][68];
    int to = t & 15, tx = t >> 4;
    int o0 = to*4, xl = tx*4;
    float acc[4][4] = {};               // [x][o]
    for (int ch = 0; ch < 14; ch++){
        const float* src; int kb, rl;
        if (ch < 4){ src = cbase; kb = ch*32; rl = 128; }
        else if (ch < 8){ src = sbase; kb = (ch-4)*32; rl = 128; }
        else if (ch < 10){ src = h; kb = (ch-8)*32; rl = 64; }
        else { src = seg; kb = (ch-10)*32; rl = 128; }
        #pragma unroll
        for (int rep = 0; rep < 2; rep++){
            int u = rep*256 + t;       // 0..511
            int xx = u >> 3, kq = u & 7;
            float4 v = *(const float4*)&src[((size_t)b*NN + x0 + xx)*rl + kb + kq*4];
            Vl[kq*4+0][xx] = v.x; Vl[kq*4+1][xx] = v.y;
            Vl[kq*4+2][xx] = v.z; Vl[kq*4+3][xx] = v.w;
        }
        #pragma unroll
        for (int rep = 0; rep < 2; rep++){
            int u = rep*256 + t;
            int oo = u >> 3, kq = u & 7;
            float4 v = *(const float4*)&Wbig[((size_t)b*CC + oo)*RDIM + ch*32 + kq*4];
            Wl[kq*4+0][oo] = v.x; Wl[kq*4+1][oo] = v.y;
            Wl[kq*4+2][oo] = v.z; Wl[kq*4+3][oo] = v.w;
        }
        __syncthreads();
        #pragma unroll
        for (int kk = 0; kk < 32; kk++){
            float4 wvec = *(float4*)&Wl[kk][o0];
            float4 vvec = *(float4*)&Vl[kk][xl];
            float wa[4] = {wvec.x, wvec.y, wvec.z, wvec.w};
            float va[4] = {vvec.x, vvec.y, vvec.z, vvec.w};
            #pragma unroll
            for (int j = 0; j < 4; j++)
                #pragma unroll
                for (int i = 0; i < 4; i++)
                    acc[j][i] += va[j] * wa[i];
        }
        __syncthreads();
    }
    float bs[4];
    #pragma unroll
    for (int i = 0; i < 4; i++) bs[i] = bias[b*CC + o0 + i];
    #pragma unroll
    for (int j = 0; j < 4; j++){
        float4 r;
        r.x = acc[j][0] + bs[0];
        r.y = acc[j][1] + bs[1];
        r.z = acc[j][2] + bs[2];
        r.w = acc[j][3] + bs[3];
        if (applyGelu){
            r.x = gelu_f(r.x); r.y = gelu_f(r.y);
            r.z = gelu_f(r.z); r.w = gelu_f(r.w);
        }
        *(float4*)&hout[((size_t)b*NN + x0 + xl + j)*CC + o0] = r;
    }
}

// ---------------------------------------------------------------- head: gelu(fc1) -> fc2 (barrier-free)
__global__ __launch_bounds__(256) void k_head(
    const float* __restrict__ h, const float* __restrict__ W1,
    const float* __restrict__ b1, const float* __restrict__ W2,
    const float* __restrict__ b2, float* __restrict__ out){
    int bid = blockIdx.x;              // B * 250
    int b = bid / 250, n0 = (bid % 250) * 64;
    int t = threadIdx.x, w = t >> 6, f = t & 63;
    __shared__ float Wl[128][65];
    #pragma unroll
    for (int r = 0; r < 8; r++){
        int u = r*256 + t;
        int ff = u >> 4, cq = u & 15;
        float4 v = *(const float4*)&W1[ff*64 + cq*4];
        Wl[ff][cq*4+0] = v.x; Wl[ff][cq*4+1] = v.y;
        Wl[ff][cq*4+2] = v.z; Wl[ff][cq*4+3] = v.w;
    }
    __syncthreads();
    float w2a = W2[f], w2b = W2[64+f];
    float b1a = b1[f], b1b = b1[64+f];
    float b2v = b2[0];
    for (int g = 0; g < 16; g++){
        int n = n0 + w*16 + g;
        float hv = h[((size_t)b*NN + n)*CC + f];
        float a1 = b1a, a2 = b1b;
        #pragma unroll
        for (int c2 = 0; c2 < 64; c2++){
            float xv = __shfl(hv, c2, 64);
            a1 += Wl[f][c2] * xv;
            a2 += Wl[64+f][c2] * xv;
        }
        float p = gelu_f(a1)*w2a + gelu_f(a2)*w2b;
        for (int off = 32; off; off >>= 1) p += __shfl_down(p, off, 64);
        if (f == 0) out[(size_t)b*NN + n] = p + b2v;
    }
}

// ---------------------------------------------------------------- host
extern "C" void kernel_launch(void* const* d_in, const int* in_sizes, int n_in,
                              void* d_out, int out_size, void* d_ws, size_t ws_size,
                              hipStream_t stream){
    const float* x_in  = (const float*)d_in[0];
    const float* nodes = (const float*)d_in[2];
    const float* nw    = (const float*)d_in[3];
    const int*   edges = (const int*)d_in[4];
    const float* egw   = (const float*)d_in[5];
    const float* modes = (const float*)d_in[6];
    const float* latent= (const float*)d_in[7];
    const float* fc0W  = (const float*)d_in[8];
    const float* fc0b  = (const float*)d_in[9];
    const float* wc    = (const float*)d_in[10];
    const float* wsp   = (const float*)d_in[11];
    const float* w0    = (const float*)d_in[12];
    const float* wsW   = (const float*)d_in[13];
    const float* wsb   = (const float*)d_in[14];
    const float* gwsW  = (const float*)d_in[15];
    const float* gwsb  = (const float*)d_in[16];
    const float* fc1W  = (const float*)d_in[17];
    const float* fc1b  = (const float*)d_in[18];
    const float* fc2W  = (const float*)d_in[19];
    const float* fc2b  = (const float*)d_in[20];
    float* out = (float*)d_out;

    char* wsbase = (char*)d_ws;
    size_t off = 0;
    auto alloc = [&](size_t bytes) -> void* {
        void* p = wsbase + off;
        off += (bytes + 255) & ~(size_t)255;
        return p;
    };
    float* cb    = (float*)alloc((size_t)BB*NN*KK*4);
    float* sb    = (float*)alloc((size_t)BB*NN*KK*4);
    float* h0    = (float*)alloc((size_t)BB*NN*CC*4);
    float* h1    = (float*)alloc((size_t)BB*NN*CC*4);
    float* seg   = (float*)alloc((size_t)BB*NN*2*CC*4);
    float* partC = (float*)alloc((size_t)BB*S1*CC*KK*4);
    float* partS = (float*)alloc((size_t)BB*S1*CC*KK*4);
    float* part0 = (float*)alloc((size_t)BB*S1*CC*4);
    float* Sc    = (float*)alloc((size_t)BB*CC*KK*4);
    float* Ss    = (float*)alloc((size_t)BB*CC*KK*4);
    float* Wbig  = (float*)alloc((size_t)BB*CC*RDIM*4);
    float* bias  = (float*)alloc((size_t)BB*CC*4);
    int*   cnt   = (int*)alloc((size_t)BB*NN*4);
    int*   rowptr= (int*)alloc((size_t)BB*(NN+4)*4);
    int*   cursor= (int*)alloc((size_t)BB*NN*4);
    int*   insrc = (int*)alloc((size_t)BB*EE*4);
    float2* inw  = (float2*)alloc((size_t)BB*EE*8);

    // bases + fc0
    k_bases<<<BB*500, 256, 0, stream>>>(nodes, modes, latent, cb, sb);
    k_fc0<<<BB*250, 256, 0, stream>>>(x_in, fc0W, fc0b, h0);

    // CSR build
    hipMemsetAsync(cnt, 0, (size_t)BB*NN*4, stream);
    csr_hist<<<(BB*EE+255)/256, 256, 0, stream>>>(edges, cnt);
    csr_scan<<<BB, 1024, 0, stream>>>(cnt, rowptr, cursor);
    csr_fill<<<(BB*EE+255)/256, 256, 0, stream>>>(edges, egw, cursor, insrc, inw);

    float* hcur = h0;
    float* hnext = h1;
    for (int l = 0; l < LL; l++){
        k1_fwd<<<BB*S1, 256, 0, stream>>>(hcur, cb, sb, nw, partC, partS, part0);
        k1_reduce<<<BB*CC, 256, 0, stream>>>(partC, partS, Sc, Ss);
        k2_mix<<<BB*CC, 256, 0, stream>>>(Sc, Ss, part0, wc, wsp, w0, wsb, gwsb,
                                          wsW, gwsW, Wbig, bias, l);
        k_grad<<<BB*1000, 256, 0, stream>>>(hcur, rowptr, insrc, inw, seg);
        k3_gemm<<<BB*250, 256, 0, stream>>>(Wbig, bias, cb, sb, hcur, seg, hnext,
                                            (l < LL-1) ? 1 : 0);
        float* tmp = hcur; hcur = hnext; hnext = tmp;
    }
    // head (hcur holds final h)
    k_head<<<BB*250, 256, 0, stream>>>(hcur, fc1W, fc1b, fc2W, fc2b, out);
    (void)in_sizes; (void)n_in; (void)out_size; (void)ws_size;
}

// Round 3
// 509.241 us; speedup vs baseline: 1.6350x; 1.0238x over previous
//
#include <hip/hip_runtime.h>
#include <math.h>

#define BB 2
#define NN 16000
#define EE 160000
#define KK 128
#define CC 64
#define LL 3

typedef __attribute__((ext_vector_type(8))) short bf16x8;
typedef __attribute__((ext_vector_type(4))) float f32x4;

__device__ __forceinline__ float gelu_f(float x){
    float x3 = x * x * x;
    return 0.5f * x * (1.f + tanhf(0.7978845608028654f * (x + 0.044715f * x3)));
}
__device__ __forceinline__ ushort f2bf(float f){
    uint u = __float_as_uint(f);
    u += 0x7fff + ((u >> 16) & 1);
    return (ushort)(u >> 16);
}
__device__ __forceinline__ float bf2f(ushort h){ return __uint_as_float(((uint)h) << 16); }
__device__ __forceinline__ void fsplit(float v, ushort &hi, ushort &lo){
    hi = f2bf(v);
    lo = f2bf(v - bf2f(hi));
}
__device__ __forceinline__ uint pk2(ushort a, ushort b){ return (uint)a | ((uint)b << 16); }

// ---------------------------------------------------------------- bases
// outputs: cb/sb x-major hi/lo [b][x][128]; wT weighted transposed hi/lo [b][256][16000]
__global__ __launch_bounds__(256) void k_bases(
    const float* __restrict__ nodes, const float* __restrict__ modes,
    const float* __restrict__ latent, const float* __restrict__ nw,
    ushort* __restrict__ cbh, ushort* __restrict__ cbl,
    ushort* __restrict__ sbh, ushort* __restrict__ sbl,
    ushort* __restrict__ wTh, ushort* __restrict__ wTl){
    int bid = blockIdx.x;              // B*250
    int b = bid / 250, x0 = (bid % 250) * 64;
    int t = threadIdx.x;
    __shared__ float sm0[128], sm1[128], nwv[64];
    __shared__ uint tc[64][65], ts[64][65];
    if (t < 128){
        float i0 = 0.5f + 1.5f / (1.f + expf(-latent[0]));
        float i1 = 0.5f + 1.5f / (1.f + expf(-latent[1]));
        sm0[t] = modes[t*2+0] * i0;
        sm1[t] = modes[t*2+1] * i1;
    }
    if (t < 64) nwv[t] = nw[b*NN + x0 + t];
    __syncthreads();
    int xloc = t & 63;
    float n0 = nodes[((size_t)b*NN + x0 + xloc)*2 + 0];
    float n1 = nodes[((size_t)b*NN + x0 + xloc)*2 + 1];
    for (int kh = 0; kh < 2; kh++){
        int kq = t >> 6;
        #pragma unroll
        for (int j = 0; j < 16; j++){
            int kl = kq*16 + j;
            int k = kh*64 + kl;
            float tmp = n0*sm0[k] + n1*sm1[k];
            float sv, cv; sincosf(tmp, &sv, &cv);
            ushort h_, l_;
            fsplit(cv, h_, l_); tc[xloc][kl] = pk2(h_, l_);
            fsplit(sv, h_, l_); ts[xloc][kl] = pk2(h_, l_);
        }
        __syncthreads();
        {   // write cb/sb x-major (lanes along k)
            int q = t >> 6;
            size_t base = ((size_t)b*NN + x0 + xloc)*128 + kh*64 + q*16;
            #pragma unroll
            for (int g2 = 0; g2 < 2; g2++){
                uint u0 = tc[xloc][q*16 + g2*8 + 0], u1 = tc[xloc][q*16 + g2*8 + 1];
                uint u2 = tc[xloc][q*16 + g2*8 + 2], u3 = tc[xloc][q*16 + g2*8 + 3];
                uint u4 = tc[xloc][q*16 + g2*8 + 4], u5 = tc[xloc][q*16 + g2*8 + 5];
                uint u6 = tc[xloc][q*16 + g2*8 + 6], u7 = tc[xloc][q*16 + g2*8 + 7];
                uint4 vh, vl;
                vh.x = pk2((ushort)u0,(ushort)u1); vh.y = pk2((ushort)u2,(ushort)u3);
                vh.z = pk2((ushort)u4,(ushort)u5); vh.w = pk2((ushort)u6,(ushort)u7);
                vl.x = pk2((ushort)(u0>>16),(ushort)(u1>>16)); vl.y = pk2((ushort)(u2>>16),(ushort)(u3>>16));
                vl.z = pk2((ushort)(u4>>16),(ushort)(u5>>16)); vl.w = pk2((ushort)(u6>>16),(ushort)(u7>>16));
                *(uint4*)&cbh[base + g2*8] = vh;
                *(uint4*)&cbl[base + g2*8] = vl;
                u0 = ts[xloc][q*16 + g2*8 + 0]; u1 = ts[xloc][q*16 + g2*8 + 1];
                u2 = ts[xloc][q*16 + g2*8 + 2]; u3 = ts[xloc][q*16 + g2*8 + 3];
                u4 = ts[xloc][q*16 + g2*8 + 4]; u5 = ts[xloc][q*16 + g2*8 + 5];
                u6 = ts[xloc][q*16 + g2*8 + 6]; u7 = ts[xloc][q*16 + g2*8 + 7];
                vh.x = pk2((ushort)u0,(ushort)u1); vh.y = pk2((ushort)u2,(ushort)u3);
                vh.z = pk2((ushort)u4,(ushort)u5); vh.w = pk2((ushort)u6,(ushort)u7);
                vl.x = pk2((ushort)(u0>>16),(ushort)(u1>>16)); vl.y = pk2((ushort)(u2>>16),(ushort)(u3>>16));
                vl.z = pk2((ushort)(u4>>16),(ushort)(u5>>16)); vl.w = pk2((ushort)(u6>>16),(ushort)(u7>>16));
                *(uint4*)&sbh[base + g2*8] = vh;
                *(uint4*)&sbl[base + g2*8] = vl;
            }
        }
        {   // write wT k-major weighted (lanes along k-rows, loop x)
            int k = t & 63, g = t >> 6;
            int kgc = kh*64 + k;
            int kgs = 128 + kh*64 + k;
            ushort hc[16], lc[16], hs[16], ls[16];
            #pragma unroll
            for (int j = 0; j < 16; j++){
                int xx = g*16 + j;
                float wgt = nwv[xx];
                uint uc = tc[xx][k], us = ts[xx][k];
                float vc = (bf2f((ushort)uc) + bf2f((ushort)(uc>>16))) * wgt;
                float vs = (bf2f((ushort)us) + bf2f((ushort)(us>>16))) * wgt;
                fsplit(vc, hc[j], lc[j]);
                fsplit(vs, hs[j], ls[j]);
            }
            size_t wbc = ((size_t)b*256 + kgc)*16000 + x0 + g*16;
            size_t wbs = ((size_t)b*256 + kgs)*16000 + x0 + g*16;
            uint4 v;
            v.x = pk2(hc[0],hc[1]); v.y = pk2(hc[2],hc[3]); v.z = pk2(hc[4],hc[5]); v.w = pk2(hc[6],hc[7]);
            *(uint4*)&wTh[wbc] = v;
            v.x = pk2(hc[8],hc[9]); v.y = pk2(hc[10],hc[11]); v.z = pk2(hc[12],hc[13]); v.w = pk2(hc[14],hc[15]);
            *(uint4*)&wTh[wbc + 8] = v;
            v.x = pk2(lc[0],lc[1]); v.y = pk2(lc[2],lc[3]); v.z = pk2(lc[4],lc[5]); v.w = pk2(lc[6],lc[7]);
            *(uint4*)&wTl[wbc] = v;
            v.x = pk2(lc[8],lc[9]); v.y = pk2(lc[10],lc[11]); v.z = pk2(lc[12],lc[13]); v.w = pk2(lc[14],lc[15]);
            *(uint4*)&wTl[wbc + 8] = v;
            v.x = pk2(hs[0],hs[1]); v.y = pk2(hs[2],hs[3]); v.z = pk2(hs[4],hs[5]); v.w = pk2(hs[6],hs[7]);
            *(uint4*)&wTh[wbs] = v;
            v.x = pk2(hs[8],hs[9]); v.y = pk2(hs[10],hs[11]); v.z = pk2(hs[12],hs[13]); v.w = pk2(hs[14],hs[15]);
            *(uint4*)&wTh[wbs + 8] = v;
            v.x = pk2(ls[0],ls[1]); v.y = pk2(ls[2],ls[3]); v.z = pk2(ls[4],ls[5]); v.w = pk2(ls[6],ls[7]);
            *(uint4*)&wTl[wbs] = v;
            v.x = pk2(ls[8],ls[9]); v.y = pk2(ls[10],ls[11]); v.z = pk2(ls[12],ls[13]); v.w = pk2(ls[14],ls[15]);
            *(uint4*)&wTl[wbs + 8] = v;
        }
        __syncthreads();
    }
}

// ---------------------------------------------------------------- shared epilogue: LDS h-tile [128x][68] -> all h formats
__device__ __forceinline__ void write_h_outputs(
    const float* ot, const float* nws, int b, int s, int x0, int t, int doAux,
    float* __restrict__ hx, ushort* __restrict__ hxh, ushort* __restrict__ hxl,
    ushort* __restrict__ hwh, ushort* __restrict__ hwl, float* __restrict__ part0){
    {
        int xl = t >> 1, half = t & 1;
        size_t gb = ((size_t)b*NN + x0 + xl)*64 + half*32;
        const float* row = &ot[xl*68 + half*32];
        #pragma unroll
        for (int j = 0; j < 8; j++){
            float4 v; v.x = row[j*4]; v.y = row[j*4+1]; v.z = row[j*4+2]; v.w = row[j*4+3];
            *(float4*)&hx[gb + j*4] = v;
        }
        if (doAux){
            #pragma unroll
            for (int q = 0; q < 4; q++){
                ushort h_[8], l_[8];
                #pragma unroll
                for (int j = 0; j < 8; j++) fsplit(row[q*8 + j], h_[j], l_[j]);
                uint4 vh, vl;
                vh.x = pk2(h_[0],h_[1]); vh.y = pk2(h_[2],h_[3]); vh.z = pk2(h_[4],h_[5]); vh.w = pk2(h_[6],h_[7]);
                vl.x = pk2(l_[0],l_[1]); vl.y = pk2(l_[2],l_[3]); vl.z = pk2(l_[4],l_[5]); vl.w = pk2(l_[6],l_[7]);
                *(uint4*)&hxh[gb + q*8] = vh;
                *(uint4*)&hxl[gb + q*8] = vl;
            }
        }
    }
    if (doAux){
        int i = t & 63, g = t >> 6;
        float a = 0.f;
        #pragma unroll
        for (int rep = 0; rep < 4; rep++){
            int xs = g*32 + rep*8;
            ushort h_[8], l_[8];
            #pragma unroll
            for (int j = 0; j < 8; j++){
                float v = ot[(xs + j)*68 + i] * nws[xs + j];
                a += v;
                fsplit(v, h_[j], l_[j]);
            }
            uint4 vh, vl;
            vh.x = pk2(h_[0],h_[1]); vh.y = pk2(h_[2],h_[3]); vh.z = pk2(h_[4],h_[5]); vh.w = pk2(h_[6],h_[7]);
            vl.x = pk2(l_[0],l_[1]); vl.y = pk2(l_[2],l_[3]); vl.z = pk2(l_[4],l_[5]); vl.w = pk2(l_[6],l_[7]);
            size_t wb = (size_t)(b*64 + i)*16000 + x0 + xs;
            *(uint4*)&hwh[wb] = vh;
            *(uint4*)&hwl[wb] = vl;
        }
        part0[((size_t)(b*125 + s)*4 + g)*64 + i] = a;
    }
}

// ---------------------------------------------------------------- fc0 (128-x blocks)
__global__ __launch_bounds__(256) void k_fc0(
    const float* __restrict__ x, const float* __restrict__ W,
    const float* __restrict__ bb, const float* __restrict__ nw,
    float* __restrict__ hx, ushort* __restrict__ hxh, ushort* __restrict__ hxl,
    ushort* __restrict__ hwh, ushort* __restrict__ hwl, float* __restrict__ part0){
    int bid = blockIdx.x;              // B*125
    int b = bid / 125, s = bid % 125;
    int x0 = s * 128;
    int t = threadIdx.x;
    __shared__ float ot[128*68];
    __shared__ float nws[128];
    __shared__ float Wf[192], bf_[64];
    if (t < 192) Wf[t] = W[t];
    if (t < 64) bf_[t] = bb[t];
    if (t < 128) nws[t] = nw[b*NN + x0 + t];
    __syncthreads();
    {
        int xl = t >> 1, half = t & 1;
        float v0 = x[((size_t)b*NN + x0 + xl)*3 + 0];
        float v1 = x[((size_t)b*NN + x0 + xl)*3 + 1];
        float v2 = x[((size_t)b*NN + x0 + xl)*3 + 2];
        #pragma unroll
        for (int j = 0; j < 32; j++){
            int o = half*32 + j;
            ot[xl*68 + o] = Wf[o*3]*v0 + Wf[o*3+1]*v1 + Wf[o*3+2]*v2 + bf_[o];
        }
    }
    __syncthreads();
    write_h_outputs(ot, nws, b, s, x0, t, 1, hx, hxh, hxl, hwh, hwl, part0);
}

// ---------------------------------------------------------------- CSR build
__global__ __launch_bounds__(256) void csr_hist(
    const int* __restrict__ edges, int* __restrict__ cnt){
    int idx = blockIdx.x * 256 + threadIdx.x;
    if (idx >= BB*EE) return;
    int b = idx / EE;
    int tgt = edges[(size_t)idx*2];
    atomicAdd(&cnt[b*NN + tgt], 1);
}

__global__ __launch_bounds__(1024) void csr_scan(
    const int* __restrict__ cnt, int* __restrict__ rowptr, int* __restrict__ cursor){
    int b = blockIdx.x;
    int t = threadIdx.x;
    __shared__ int lds[1024];
    int base = t * 16;
    int v[16];
    int run = 0;
    #pragma unroll
    for (int j = 0; j < 16; j++){
        int n = base + j;
        int c = (n < NN) ? cnt[b*NN + n] : 0;
        v[j] = run;
        run += c;
    }
    lds[t] = run;
    __syncthreads();
    for (int off = 1; off < 1024; off <<= 1){
        int xv = (t >= off) ? lds[t-off] : 0;
        __syncthreads();
        lds[t] += xv;
        __syncthreads();
    }
    int toff = lds[t] - run;  // exclusive
    #pragma unroll
    for (int j = 0; j < 16; j++){
        int n = base + j;
        if (n < NN){
            int p = toff + v[j];
            rowptr[b*(NN+1) + n] = p;
            cursor[b*NN + n] = p;
        }
    }
    if (t == 1023) rowptr[b*(NN+1) + NN] = lds[1023];
}

__global__ __launch_bounds__(256) void csr_fill(
    const int* __restrict__ edges, const float* __restrict__ egw,
    int* __restrict__ cursor, int* __restrict__ insrc, float2* __restrict__ inw){
    int idx = blockIdx.x * 256 + threadIdx.x;
    if (idx >= BB*EE) return;
    int b = idx / EE;
    int tgt = edges[(size_t)idx*2];
    int src = edges[(size_t)idx*2 + 1];
    int pos = atomicAdd(&cursor[b*NN + tgt], 1);
    insrc[(size_t)b*EE + pos] = src;
    const float2 wv = *(const float2*)&egw[(size_t)idx*2];
    inw[(size_t)b*EE + pos] = wv;
}

// ---------------------------------------------------------------- forward transform: MFMA, split-bf16
// part[b][s(250)][i(64)][k(256)] partials; A = hw[i][x] hi/lo, B = wT[k][x] hi/lo
__global__ __launch_bounds__(256) void k1_fwd(
    const ushort* __restrict__ hwH, const ushort* __restrict__ hwL,
    const ushort* __restrict__ wTH, const ushort* __restrict__ wTL,
    float* __restrict__ part){
    int bid = blockIdx.x;              // B*250
    int b = bid / 250, s = bid % 250;
    int x0 = s * 64;
    int t = threadIdx.x, l = t & 63, w = t >> 6;
    __shared__ __align__(16) ushort Bh[128*64], Bl[128*64];
    f32x4 acc[16] = {};
    bf16x8 Ah[2], Al[2];
    int i = w*16 + (l & 15);
    #pragma unroll
    for (int ks = 0; ks < 2; ks++){
        size_t ab = (size_t)(b*64 + i)*16000 + x0 + ks*32 + ((l >> 4) * 8);
        Ah[ks] = *reinterpret_cast<const bf16x8*>(&hwH[ab]);
        Al[ks] = *reinterpret_cast<const bf16x8*>(&hwL[ab]);
    }
    for (int p = 0; p < 2; p++){
        #pragma unroll
        for (int it = 0; it < 4; it++){
            int u = it*256 + t;
            int kloc = u >> 3, q = u & 7;
            size_t g = ((size_t)(b*256 + p*128 + kloc))*16000 + x0 + q*8;
            uint4 vh = *(const uint4*)&wTH[g];
            uint4 vl = *(const uint4*)&wTL[g];
            int ldsb = kloc*128 + ((q*16) ^ ((kloc & 7) << 4));
            *(uint4*)&Bh[ldsb >> 1] = vh;
            *(uint4*)&Bl[ldsb >> 1] = vl;
        }
        __syncthreads();
        #pragma unroll
        for (int kt = 0; kt < 8; kt++){
            int kcol = kt*16 + (l & 15);
            int ai = p*8 + kt;
            #pragma unroll
            for (int ks = 0; ks < 2; ks++){
                int boff = kcol*128 + (((ks*64) + ((l >> 4) * 16)) ^ ((kcol & 7) << 4));
                bf16x8 bh = *reinterpret_cast<const bf16x8*>(&Bh[boff >> 1]);
                bf16x8 bl = *reinterpret_cast<const bf16x8*>(&Bl[boff >> 1]);
                acc[ai] = __builtin_amdgcn_mfma_f32_16x16x32_bf16(Ah[ks], bh, acc[ai], 0, 0, 0);
                acc[ai] = __builtin_amdgcn_mfma_f32_16x16x32_bf16(Ah[ks], bl, acc[ai], 0, 0, 0);
                acc[ai] = __builtin_amdgcn_mfma_f32_16x16x32_bf16(Al[ks], bh, acc[ai], 0, 0, 0);
            }
        }
        __syncthreads();
    }
    size_t pb = (size_t)(b*250 + s) * 64 * 256;
    #pragma unroll
    for (int nt = 0; nt < 16; nt++){
        #pragma unroll
        for (int r = 0; r < 4; r++){
            int irow = w*16 + (l >> 4)*4 + r;
            part[pb + (size_t)irow*256 + nt*16 + (l & 15)] = acc[nt][r];
        }
    }
}

// ---------------------------------------------------------------- partial reduce
__global__ __launch_bounds__(512) void k1_reduce(
    const float* __restrict__ part, float* __restrict__ Sc, float* __restrict__ Ss){
    int b = blockIdx.x >> 6, i = blockIdx.x & 63;   // grid B*64
    int t = threadIdx.x;
    int c = t & 255, sh = t >> 8;
    float a0=0,a1=0,a2=0,a3=0;
    int j = sh;
    for (; j + 6 < 250; j += 8){
        a0 += part[((size_t)(b*250 + j    )*64 + i)*256 + c];
        a1 += part[((size_t)(b*250 + j + 2)*64 + i)*256 + c];
        a2 += part[((size_t)(b*250 + j + 4)*64 + i)*256 + c];
        a3 += part[((size_t)(b*250 + j + 6)*64 + i)*256 + c];
    }
    for (; j < 250; j += 2)
        a0 += part[((size_t)(b*250 + j)*64 + i)*256 + c];
    float sum = (a0+a1)+(a2+a3);
    __shared__ float r2[256];
    if (sh) r2[c] = sum;
    __syncthreads();
    if (!sh){
        sum += r2[c];
        if (c < 128) Sc[(size_t)(b*64 + i)*128 + c] = sum;
        else         Ss[(size_t)(b*64 + i)*128 + (c - 128)] = sum;
    }
}

// ---------------------------------------------------------------- per-mode channel mix -> Wbig(hi/lo), bias
__global__ __launch_bounds__(256) void k2_mix(
    const float* __restrict__ Sc, const float* __restrict__ Ss,
    const float* __restrict__ part0,
    const float* __restrict__ wc, const float* __restrict__ wsp,
    const float* __restrict__ w0,
    const float* __restrict__ wsb, const float* __restrict__ gwsb,
    const float* __restrict__ wsW, const float* __restrict__ gwsW,
    ushort* __restrict__ WbH, ushort* __restrict__ WbL,
    float* __restrict__ bias, int l){
    int b = blockIdx.x >> 6, o = blockIdx.x & 63;
    int t = threadIdx.x;
    __shared__ float fc2s[2][128], fs2s[2][128];
    __shared__ float red[64];
    if (t < 64){
        float x0 = 0.f;
        for (int s2 = 0; s2 < 500; s2++) x0 += part0[(size_t)(b*500 + s2)*64 + t];
        red[t] = x0 * w0[((size_t)l*CC + t)*CC + o];
    }
    int k = t & 127, hf = t >> 7;
    float fc = 0.f, fs = 0.f;
    for (int i = hf*32; i < hf*32 + 32; i++){
        float sc = Sc[(size_t)(b*CC + i)*KK + k];
        float ss = Ss[(size_t)(b*CC + i)*KK + k];
        size_t wi = (((size_t)l*CC + i)*CC + o)*KK + k;
        float a = wc[wi], bb2 = wsp[wi];
        fc += sc*a + ss*bb2;
        fs += sc*bb2 - ss*a;
    }
    fc2s[hf][k] = fc; fs2s[hf][k] = fs;
    __syncthreads();
    size_t wb = (size_t)(b*CC + o) * 448;
    if (t < 128){
        float FC = fc2s[0][t] + fc2s[1][t];
        float FS = fs2s[0][t] + fs2s[1][t];
        ushort h_, l_;
        fsplit(2.f*FC, h_, l_);
        WbH[wb + t] = h_; WbL[wb + t] = l_;
        fsplit(-2.f*FS, h_, l_);
        WbH[wb + 128 + t] = h_; WbL[wb + 128 + t] = l_;
    }
    if (t < 192){
        float v = (t < 64) ? wsW[((size_t)l*CC + o)*CC + t]
                           : gwsW[((size_t)l*CC + o)*128 + (t - 64)];
        ushort h_, l_; fsplit(v, h_, l_);
        WbH[wb + 256 + t] = h_; WbL[wb + 256 + t] = l_;
    }
    if (t == 0){
        float f0 = 0.f;
        for (int i = 0; i < 64; i++) f0 += red[i];
        bias[b*CC + o] = f0 + wsb[l*CC + o] + gwsb[l*CC + o];
    }
}

// ---------------------------------------------------------------- gradient field (CSR, atomic-free) -> seg hi/lo
__global__ __launch_bounds__(256) void k_grad(
    const float* __restrict__ h, const int* __restrict__ rowptr,
    const int* __restrict__ insrc, const float2* __restrict__ inw,
    ushort* __restrict__ segh, ushort* __restrict__ segl){
    int bid = blockIdx.x;              // B * 2000
    int b = bid / 2000, n0 = (bid % 2000) * 8;
    int w = threadIdx.x >> 6, c = threadIdx.x & 63;
    const float*  hb  = h + (size_t)b*NN*CC;
    const int*    isb = insrc + (size_t)b*EE;
    const float2* iwb = inw + (size_t)b*EE;
    #pragma unroll
    for (int g = 0; g < 2; g++){
        int n = n0 + w*2 + g;
        float hn = hb[(size_t)n*CC + c];
        int p0 = rowptr[b*(NN+1) + n];
        int p1 = rowptr[b*(NN+1) + n + 1];
        float a0 = 0.f, a1 = 0.f;
        int p = p0;
        for (; p + 4 <= p1; p += 4){
            int s0 = isb[p], s1 = isb[p+1], s2 = isb[p+2], s3 = isb[p+3];
            float2 w0 = iwb[p], w1 = iwb[p+1], w2 = iwb[p+2], w3 = iwb[p+3];
            float d0 = hb[(size_t)s0*CC + c] - hn;
            float d1 = hb[(size_t)s1*CC + c] - hn;
            float d2 = hb[(size_t)s2*CC + c] - hn;
            float d3 = hb[(size_t)s3*CC + c] - hn;
            a0 += w0.x*d0 + w1.x*d1 + w2.x*d2 + w3.x*d3;
            a1 += w0.y*d0 + w1.y*d1 + w2.y*d2 + w3.y*d3;
        }
        for (; p < p1; p++){
            int sx = isb[p]; float2 ww = iwb[p];
            float d = hb[(size_t)sx*CC + c] - hn;
            a0 += ww.x*d; a1 += ww.y*d;
        }
        ushort h0_, l0_, h1_, l1_;
        fsplit(a0, h0_, l0_);
        fsplit(a1, h1_, l1_);
        size_t sb2 = ((size_t)b*NN + n)*128 + 2*c;
        *(uint*)&segh[sb2] = pk2(h0_, h1_);
        *(uint*)&segl[sb2] = pk2(l0_, l1_);
    }
}

// ---------------------------------------------------------------- layer output GEMM (MFMA split-bf16)
// h_new[o][x] = gelu(Wbig[o][:] . V[:][x] + bias[o]); V comps: cos128|sin128|h64|seg128
__global__ __launch_bounds__(256) void k3_gemm(
    const ushort* __restrict__ WbH, const ushort* __restrict__ WbL,
    const float* __restrict__ bias,
    const ushort* __restrict__ cbh, const ushort* __restrict__ cbl,
    const ushort* __restrict__ sbh, const ushort* __restrict__ sbl,
    const ushort* __restrict__ hxh, const ushort* __restrict__ hxl,
    const ushort* __restrict__ sgh, const ushort* __restrict__ sgl,
    const float* __restrict__ nw,
    float* __restrict__ hxO, ushort* __restrict__ hxhO, ushort* __restrict__ hxlO,
    ushort* __restrict__ hwhO, ushort* __restrict__ hwlO, float* __restrict__ part0,
    int doAux){
    int bid = blockIdx.x;              // B*125
    int b = bid / 125, s = bid % 125, x0 = s * 128;
    int t = threadIdx.x, l = t & 63, w = t >> 6;
    __shared__ __align__(16) char smem[34816];
    ushort* Vh = (ushort*)smem;
    ushort* Vl = Vh + 8192;
    __shared__ float nws[128];
    if (t < 128) nws[t] = nw[b*NN + x0 + t];
    f32x4 acc[8] = {};
    int o = w*16 + (l & 15);
    for (int cc = 0; cc < 7; cc++){
        const ushort *srcH, *srcL; int rl, co;
        switch (cc){
            case 0:  srcH = cbh; srcL = cbl; rl = 128; co = 0;  break;
            case 1:  srcH = cbh; srcL = cbl; rl = 128; co = 64; break;
            case 2:  srcH = sbh; srcL = sbl; rl = 128; co = 0;  break;
            case 3:  srcH = sbh; srcL = sbl; rl = 128; co = 64; break;
            case 4:  srcH = hxh; srcL = hxl; rl = 64;  co = 0;  break;
            case 5:  srcH = sgh; srcL = sgl; rl = 128; co = 0;  break;
            default: srcH = sgh; srcL = sgl; rl = 128; co = 64; break;
        }
        __syncthreads();
        #pragma unroll
        for (int it = 0; it < 4; it++){
            int u = it*256 + t;
            int xl2 = u >> 3, q = u & 7;
            size_t g = (size_t)(b*NN + x0 + xl2)*rl + co + q*8;
            uint4 vh = *(const uint4*)&srcH[g];
            uint4 vl2 = *(const uint4*)&srcL[g];
            int ldsb = xl2*128 + ((q*16) ^ ((xl2 & 7) << 4));
            *(uint4*)&Vh[ldsb >> 1] = vh;
            *(uint4*)&Vl[ldsb >> 1] = vl2;
        }
        __syncthreads();
        bf16x8 Ah[2], Al[2];
        #pragma unroll
        for (int ks = 0; ks < 2; ks++){
            size_t ab = (size_t)(b*64 + o)*448 + cc*64 + ks*32 + ((l >> 4) * 8);
            Ah[ks] = *reinterpret_cast<const bf16x8*>(&WbH[ab]);
            Al[ks] = *reinterpret_cast<const bf16x8*>(&WbL[ab]);
        }
        #pragma unroll
        for (int nt = 0; nt < 8; nt++){
            int xc = nt*16 + (l & 15);
            #pragma unroll
            for (int ks = 0; ks < 2; ks++){
                int boff = xc*128 + (((ks*64) + ((l >> 4) * 16)) ^ ((xc & 7) << 4));
                bf16x8 bh = *reinterpret_cast<const bf16x8*>(&Vh[boff >> 1]);
                bf16x8 bl = *reinterpret_cast<const bf16x8*>(&Vl[boff >> 1]);
                acc[nt] = __builtin_amdgcn_mfma_f32_16x16x32_bf16(Ah[ks], bh, acc[nt], 0, 0, 0);
                acc[nt] = __builtin_amdgcn_mfma_f32_16x16x32_bf16(Ah[ks], bl, acc[nt], 0, 0, 0);
                acc[nt] = __builtin_amdgcn_mfma_f32_16x16x32_bf16(Al[ks], bh, acc[nt], 0, 0, 0);
            }
        }
    }
    __syncthreads();
    float* ot = (float*)smem;          // reuse as [128][68]
    float bv[4];
    #pragma unroll
    for (int r = 0; r < 4; r++) bv[r] = bias[b*64 + w*16 + (l >> 4)*4 + r];
    #pragma unroll
    for (int nt = 0; nt < 8; nt++){
        int xc = nt*16 + (l & 15);
        #pragma unroll
        for (int r = 0; r < 4; r++){
            float v = acc[nt][r] + bv[r];
            if (doAux) v = gelu_f(v);
            ot[xc*68 + (w*16 + (l >> 4)*4 + r)] = v;
        }
    }
    __syncthreads();
    write_h_outputs(ot, nws, b, s, x0, t, doAux, hxO, hxhO, hxlO, hwhO, hwlO, part0);
}

// ---------------------------------------------------------------- head: gelu(fc1) -> fc2
__global__ __launch_bounds__(256) void k_head(
    const float* __restrict__ h, const float* __restrict__ W1,
    const float* __restrict__ b1, const float* __restrict__ W2,
    const float* __restrict__ b2, float* __restrict__ out){
    int bid = blockIdx.x;              // B * 250
    int b = bid / 250, n0 = (bid % 250) * 64;
    int t = threadIdx.x, w = t >> 6, f = t & 63;
    __shared__ float Wl[128][65];
    #pragma unroll
    for (int r = 0; r < 8; r++){
        int u = r*256 + t;
        int ff = u >> 4, cq = u & 15;
        float4 v = *(const float4*)&W1[ff*64 + cq*4];
        Wl[ff][cq*4+0] = v.x; Wl[ff][cq*4+1] = v.y;
        Wl[ff][cq*4+2] = v.z; Wl[ff][cq*4+3] = v.w;
    }
    __syncthreads();
    float w2a = W2[f], w2b = W2[64+f];
    float b1a = b1[f], b1b = b1[64+f];
    float b2v = b2[0];
    for (int g = 0; g < 16; g++){
        int n = n0 + w*16 + g;
        float hv = h[((size_t)b*NN + n)*CC + f];
        float a1 = b1a, a2 = b1b;
        #pragma unroll
        for (int c2 = 0; c2 < 64; c2++){
            float xv = __shfl(hv, c2, 64);
            a1 += Wl[f][c2] * xv;
            a2 += Wl[64+f][c2] * xv;
        }
        float p = gelu_f(a1)*w2a + gelu_f(a2)*w2b;
        for (int off = 32; off; off >>= 1) p += __shfl_down(p, off, 64);
        if (f == 0) out[(size_t)b*NN + n] = p + b2v;
    }
}

// ---------------------------------------------------------------- host
extern "C" void kernel_launch(void* const* d_in, const int* in_sizes, int n_in,
                              void* d_out, int out_size, void* d_ws, size_t ws_size,
                              hipStream_t stream){
    const float* x_in  = (const float*)d_in[0];
    const float* nodes = (const float*)d_in[2];
    const float* nw    = (const float*)d_in[3];
    const int*   edges = (const int*)d_in[4];
    const float* egw   = (const float*)d_in[5];
    const float* modes = (const float*)d_in[6];
    const float* latent= (const float*)d_in[7];
    const float* fc0W  = (const float*)d_in[8];
    const float* fc0b  = (const float*)d_in[9];
    const float* wc    = (const float*)d_in[10];
    const float* wsp   = (const float*)d_in[11];
    const float* w0    = (const float*)d_in[12];
    const float* wsW   = (const float*)d_in[13];
    const float* wsb   = (const float*)d_in[14];
    const float* gwsW  = (const float*)d_in[15];
    const float* gwsb  = (const float*)d_in[16];
    const float* fc1W  = (const float*)d_in[17];
    const float* fc1b  = (const float*)d_in[18];
    const float* fc2W  = (const float*)d_in[19];
    const float* fc2b  = (const float*)d_in[20];
    float* out = (float*)d_out;

    char* wsbase = (char*)d_ws;
    size_t off = 0;
    auto alloc = [&](size_t bytes) -> void* {
        void* p = wsbase + off;
        off += (bytes + 255) & ~(size_t)255;
        return p;
    };
    ushort* cbh = (ushort*)alloc((size_t)BB*NN*128*2);
    ushort* cbl = (ushort*)alloc((size_t)BB*NN*128*2);
    ushort* sbh = (ushort*)alloc((size_t)BB*NN*128*2);
    ushort* sbl = (ushort*)alloc((size_t)BB*NN*128*2);
    ushort* wTh = (ushort*)alloc((size_t)BB*256*NN*2);
    ushort* wTl = (ushort*)alloc((size_t)BB*256*NN*2);
    float*  hx[2];  ushort* hxh[2]; ushort* hxl[2]; ushort* hwh[2]; ushort* hwl[2];
    for (int i = 0; i < 2; i++){
        hx[i]  = (float*) alloc((size_t)BB*NN*64*4);
        hxh[i] = (ushort*)alloc((size_t)BB*NN*64*2);
        hxl[i] = (ushort*)alloc((size_t)BB*NN*64*2);
        hwh[i] = (ushort*)alloc((size_t)BB*64*NN*2);
        hwl[i] = (ushort*)alloc((size_t)BB*64*NN*2);
    }
    ushort* segh = (ushort*)alloc((size_t)BB*NN*128*2);
    ushort* segl = (ushort*)alloc((size_t)BB*NN*128*2);
    float*  part = (float*) alloc((size_t)BB*250*64*256*4);
    float*  part0= (float*) alloc((size_t)BB*125*4*64*4);
    float*  Sc   = (float*) alloc((size_t)BB*64*128*4);
    float*  Ss   = (float*) alloc((size_t)BB*64*128*4);
    ushort* WbH  = (ushort*)alloc((size_t)BB*64*448*2);
    ushort* WbL  = (ushort*)alloc((size_t)BB*64*448*2);
    float*  bias = (float*) alloc((size_t)BB*64*4);
    int*   cnt   = (int*)   alloc((size_t)BB*NN*4);
    int*   rowptr= (int*)   alloc((size_t)BB*(NN+4)*4);
    int*   cursor= (int*)   alloc((size_t)BB*NN*4);
    int*   insrc = (int*)   alloc((size_t)BB*EE*4);
    float2* inw  = (float2*)alloc((size_t)BB*EE*8);

    k_bases<<<BB*250, 256, 0, stream>>>(nodes, modes, latent, nw,
                                        cbh, cbl, sbh, sbl, wTh, wTl);
    k_fc0<<<BB*125, 256, 0, stream>>>(x_in, fc0W, fc0b, nw,
                                      hx[0], hxh[0], hxl[0], hwh[0], hwl[0], part0);

    hipMemsetAsync(cnt, 0, (size_t)BB*NN*4, stream);
    csr_hist<<<(BB*EE+255)/256, 256, 0, stream>>>(edges, cnt);
    csr_scan<<<BB, 1024, 0, stream>>>(cnt, rowptr, cursor);
    csr_fill<<<(BB*EE+255)/256, 256, 0, stream>>>(edges, egw, cursor, insrc, inw);

    int cur = 0;
    for (int l = 0; l < LL; l++){
        int nxt = cur ^ 1;
        int doAux = (l < LL-1) ? 1 : 0;
        k1_fwd<<<BB*250, 256, 0, stream>>>(hwh[cur], hwl[cur], wTh, wTl, part);
        k1_reduce<<<BB*64, 512, 0, stream>>>(part, Sc, Ss);
        k2_mix<<<BB*64, 256, 0, stream>>>(Sc, Ss, part0, wc, wsp, w0, wsb, gwsb,
                                          wsW, gwsW, WbH, WbL, bias, l);
        k_grad<<<BB*2000, 256, 0, stream>>>(hx[cur], rowptr, insrc, inw, segh, segl);
        k3_gemm<<<BB*125, 256, 0, stream>>>(WbH, WbL, bias,
                                            cbh, cbl, sbh, sbl,
                                            hxh[cur], hxl[cur], segh, segl, nw,
                                            hx[nxt], hxh[nxt], hxl[nxt],
                                            hwh[nxt], hwl[nxt], part0, doAux);
        cur = nxt;
    }
    k_head<<<BB*250, 256, 0, stream>>>(hx[cur], fc1W, fc1b, fc2W, fc2b, out);
    (void)in_sizes; (void)n_in; (void)out_size; (void)ws_size; (void)segh; (void)segl;
}